// Round 14
// baseline (13188.025 us; speedup 1.0000x reference)
//
#include <hip/hip_runtime.h>
#include <stdint.h>

// PolicyNetRSNNPB R14: two independent group-chains per CU.
// R13: 1024-thr blocks always compile to 64 VGPR -> serialized gather + FETCH
// explosion. Instead of widening one chain, co-schedule TWO independent ones:
// grid 512 x 512thr (33KB LDS, <=128 VGPR) -> 2 blocks/CU, block = one group
// of 8 samples (wave = 1 sample). Group A's exchange wait hides under group
// B's gather. x = blockIdx&7 (round-robin ~= physical XCD; perf-only).
// Also: merged single drain per step, zero-row unguarded gather, setprio(1)
// around gather, sleep(1) polls, full-length lists. SPW=2/grid-256 fallback
// if occupancy < 2 blocks/CU. Bit-exact order preserved (absmax 0.0).

typedef unsigned long long u64;
typedef unsigned int u32;
typedef float f32x4 __attribute__((ext_vector_type(4)));

#define NB 512
#define HD 2048
#define ROWS 2049          // 2048 + zero row
#define NSTEPS 128
#define THREADS 512
#define COLS 256
#define NWPS 32
#define LSTN 2080          // full 2048 + pad; 8*2080*2B = 33,280B LDS
#define ZROW 2048

#define DMc 0.8187307530779818f
#define DSc 0.6065306597126334f
#define SMc 0.18126924692201818f

// ---- ws layout ----
#define OFF_M1W 0
#define SZ_M1W ((size_t)2 * NB * NWPS * 8)       // 256 KB
#define OFF_M2H (OFF_M1W + SZ_M1W)
#define SZ_M2H ((size_t)NSTEPS * NB * NWPS * 8)  // 16 MB
#define OFF_SLOT (OFF_M2H + SZ_M2H)              // u32 per (g,x), 128B stride
#define SZ_SLOT (64 * 8 * 128)
#define OFF_DONE (OFF_SLOT + SZ_SLOT)
#define OFF_PK (((size_t)(OFF_DONE + 64) + 4194303) & ~(size_t)4194303)
#define SZ_PK ((size_t)8 * ROWS * 512 * 4)       // ~33.6 MB
#define OFF_XW (((OFF_PK + SZ_PK) + 255) & ~(size_t)255)
#define SZ_XW ((size_t)64 * NB * HD * 4)         // 256 MB

#define SLOT(base, g, x) ((base) + ((size_t)((g)*8 + (x)) * 32))

__global__ void init_ws(u64* __restrict__ m1W, u32* __restrict__ slots,
                        u32* __restrict__ done) {
  int i = blockIdx.x * 256 + threadIdx.x;
  if (i < 2 * NB * NWPS) m1W[i] = 0ULL;
  if (i < 64 * 8 * 32) slots[i] = 0u;
  if (i == 0) *done = 0u;
}

// PK[x][k][0..255]=Vr[k][x*256+..], [256..511]=Wf[k][..]; row 2048 = zeros
__global__ __launch_bounds__(256) void pack_kernel(
    const float* __restrict__ Vr, const float* __restrict__ Wf,
    float* __restrict__ PK) {
  const int k = blockIdx.x;
  const int tid = threadIdx.x;
  for (int c = tid; c < HD; c += 256) {
    int x = c >> 8, cc = c & 255;
    size_t base = ((size_t)x * ROWS + k) * 512;
    float v = (k < HD) ? Vr[(size_t)k * HD + c] : 0.0f;
    float w = (k < HD) ? Wf[(size_t)k * HD + c] : 0.0f;
    __builtin_nontemporal_store(v, &PK[base + cc]);
    __builtin_nontemporal_store(w, &PK[base + 256 + cc]);
  }
}

// XW[t*NB+n][h] = bi[h] + x(t,n,:) @ Wi
__global__ __launch_bounds__(256) void xw_kernel(
    const float* __restrict__ state, const float* __restrict__ target,
    const float* __restrict__ Wi, const float* __restrict__ bi,
    float* __restrict__ XW) {
  __shared__ float xl[16][128];
  const int tid = threadIdx.x;
  const int col = blockIdx.x * 256 + tid;
  const int r0 = blockIdx.y * 16;

  for (int idx = tid; idx < 16 * 128; idx += 256) {
    int r = idx >> 7, k = idx & 127;
    int gg = r0 + r;
    int t = gg >> 9, n = gg & 511;
    float v = (k < 64) ? state[((size_t)(t * NB + n)) * 64 + k]
                       : target[((size_t)(t * NB + n)) * 64 + (k - 64)];
    xl[r][k] = v;
  }
  __syncthreads();

  float acc[16];
  float b = bi[col];
#pragma unroll
  for (int r = 0; r < 16; ++r) acc[r] = b;
  for (int k = 0; k < 128; ++k) {
    float w = Wi[(size_t)k * HD + col];
#pragma unroll
    for (int r = 0; r < 16; ++r) acc[r] = fmaf(xl[r][k], w, acc[r]);
  }
#pragma unroll
  for (int r = 0; r < 16; ++r)
    __builtin_nontemporal_store(acc[r], &XW[(size_t)(r0 + r) * HD + col]);
}

__device__ __forceinline__ u64 spread4(u64 x) {
  x &= 0xffffULL;
  x = (x | (x << 24)) & 0x000000FF000000FFULL;
  x = (x | (x << 12)) & 0x000F000F000F000FULL;
  x = (x | (x << 6))  & 0x0303030303030303ULL;
  x = (x | (x << 3))  & 0x1111111111111111ULL;
  return x;
}

__device__ __forceinline__ u64 pack_word(u64 B0, u64 B1, u64 B2, u64 B3, int q) {
  int sh = q * 16;
  return spread4(B0 >> sh) | (spread4(B1 >> sh) << 1) |
         (spread4(B2 >> sh) << 2) | (spread4(B3 >> sh) << 3);
}

// one-sample list build from MALL masks; ascending; pad to x8 with ZROW.
__device__ __forceinline__ int build_one(const u64* __restrict__ mw,
                                         uint16_t* __restrict__ lst, int lane) {
  u64 w = 0ULL;
  if (lane < NWPS)
    w = __hip_atomic_load((u64*)&mw[lane], __ATOMIC_RELAXED,
                          __HIP_MEMORY_SCOPE_AGENT);
  int pc = __popcll(w);
  int pre = pc;
#pragma unroll
  for (int off = 1; off < 64; off <<= 1) {
    int v = __shfl_up(pre, off);
    if (lane >= off) pre += v;
  }
  int excl = pre - pc;
  int total = __shfl(pre, 63);
  int kb = lane << 6;
  while (w) {
    int b = __builtin_ctzll(w);
    w &= w - 1;
    lst[excl++] = (uint16_t)(kb + b);
  }
  int r8 = (total + 7) & ~7;
  if (lane < 8 && total + lane < r8) lst[total + lane] = (uint16_t)ZROW;
  asm volatile("s_waitcnt lgkmcnt(0)" ::: "memory");
  return r8;
}

// readout-tail list build (plain loads)
__device__ __forceinline__ int build_list_ro(const u64* __restrict__ mwords,
                                             uint16_t* __restrict__ lstw,
                                             int lane) {
  u64 w = (lane < NWPS) ? mwords[lane] : 0ULL;
  int pc = __popcll(w);
  int pre = pc;
#pragma unroll
  for (int off = 1; off < 64; off <<= 1) {
    int v = __shfl_up(pre, off);
    if (lane >= off) pre += v;
  }
  int excl = pre - pc;
  int total = __shfl(pre, 63);
  int kb = lane << 6;
  while (w) {
    int b = __builtin_ctzll(w);
    w &= w - 1;
    lstw[excl++] = (uint16_t)(kb + b);
  }
  asm volatile("s_waitcnt lgkmcnt(0)" ::: "memory");
  return total;
}

__device__ __forceinline__ u32 lif_update(const float acc[4], float syn[4],
                                          float mem[4], u32 snib) {
  u32 nib = 0;
#pragma unroll
  for (int j = 0; j < 4; ++j) {
    float so = (float)((snib >> j) & 1u);
    float nmem = (DMc * mem[j] + SMc * syn[j]) * (1.0f - so);  // R1 shape
    float nsyn = DSc * syn[j] + acc[j];                         // R1 shape
    mem[j] = nmem;
    syn[j] = nsyn;
    if ((nmem - 1.0f) > 0.0f) nib |= (1u << j);
  }
  return nib;
}

// unguarded dual gather (zero-row padded list): addr + 2 loads + 8 adds per
// element, 16 loads in flight, ascending k; trailing +0.0 adds exact.
__device__ __forceinline__ void gather_one(const float* __restrict__ PKb,
                                           const uint16_t* __restrict__ lst,
                                           int r8, float aV[4], float aW[4]) {
  for (int j0 = 0; j0 < r8; j0 += 8) {
    f32x4 v[8], w8[8];
#pragma unroll
    for (int u = 0; u < 8; ++u) {
      size_t off = ((size_t)lst[j0 + u]) << 9;
      v[u] = *(const f32x4*)(PKb + off);
      w8[u] = *(const f32x4*)(PKb + off + 256);
    }
#pragma unroll
    for (int u = 0; u < 8; ++u) {
      aV[0] += v[u].x; aV[1] += v[u].y; aV[2] += v[u].z; aV[3] += v[u].w;
      aW[0] += w8[u].x; aW[1] += w8[u].y; aW[2] += w8[u].z; aW[3] += w8[u].w;
    }
  }
}

// SPW = samples per wave (1: grid 512, 2 blocks/CU; 2: grid 256 fallback)
template <int SPW, int UXW>
__global__ __launch_bounds__(THREADS, 4) void rsnn_coop(
    const float* __restrict__ state, const float* __restrict__ target,
    const float* __restrict__ Wi, const float* __restrict__ bi,
    const float* __restrict__ Vr, const float* __restrict__ Wf,
    const float* __restrict__ bf, const float* __restrict__ Wo,
    const float* __restrict__ bo, float* __restrict__ out,
    char* __restrict__ wsb) {
  __shared__ uint16_t lst_s[8][LSTN];   // 33,280 B -> 2 blocks/CU possible

  u64* m1W = (u64*)(wsb + OFF_M1W);
  u64* m2H = (u64*)(wsb + OFF_M2H);
  u32* slots = (u32*)(wsb + OFF_SLOT);
  u32* done = (u32*)(wsb + OFF_DONE);
  const float* PK = (const float*)(wsb + OFF_PK);
  const float* XW = (const float*)(wsb + OFF_XW);

  const int tid = threadIdx.x;
  const int wv = tid >> 6;      // 0..7
  const int lane = tid & 63;    // lane = 4 columns

  const int x = blockIdx.x & 7;          // column-slice owner (~physical XCD)
  const int g = blockIdx.x >> 3;         // group id (64/SPW groups)
  const int c0 = x * COLS;
  const int s0 = (g * 8 + wv) * SPW;     // first sample of this wave

  uint16_t* lst = &lst_s[wv][0];

  float bir[4], bfr[4];
#pragma unroll
  for (int j = 0; j < 4; ++j) {
    bir[j] = bi[c0 + lane * 4 + j];
    bfr[j] = bf[c0 + lane * 4 + j];
  }

  float syn1[SPW][4], mem1[SPW][4], syn2[SPW][4], mem2[SPW][4];
#pragma unroll
  for (int r = 0; r < SPW; ++r)
#pragma unroll
    for (int j = 0; j < 4; ++j) {
      syn1[r][j] = 0.f; mem1[r][j] = 0.f; syn2[r][j] = 0.f; mem2[r][j] = 0.f;
    }
  u32 nib1[SPW], nib2[SPW];
#pragma unroll
  for (int r = 0; r < SPW; ++r) { nib1[r] = 0u; nib2[r] = 0u; }
  float xw[SPW][4];
  f32x4 xwN[SPW];

  const float* PKb = PK + (size_t)x * ROWS * 512 + lane * 4;
  const float* XWc = XW + c0 + lane * 4;

  // fallback xw (k-ascending fmaf from global Wi)
  auto compute_xw = [&](int t2, int r) {
#pragma unroll
    for (int j = 0; j < 4; ++j) xw[r][j] = bir[j];
#pragma unroll
    for (int half = 0; half < 2; ++half) {
      const float* p =
          (half ? target : state) + ((size_t)t2 * NB + s0 + r) * 64;
      for (int q = 0; q < 16; ++q) {
        f32x4 xq = *(const f32x4*)(p + 4 * q);
        float xv[4] = {xq.x, xq.y, xq.z, xq.w};
#pragma unroll
        for (int kj = 0; kj < 4; ++kj) {
          const f32x4 w4 = *(const f32x4*)&Wi[(size_t)(half * 64 + 4 * q + kj) *
                                                  HD + c0 + lane * 4];
          xw[r][0] = fmaf(xv[kj], w4.x, xw[r][0]);
          xw[r][1] = fmaf(xv[kj], w4.y, xw[r][1]);
          xw[r][2] = fmaf(xv[kj], w4.z, xw[r][2]);
          xw[r][3] = fmaf(xv[kj], w4.w, xw[r][3]);
        }
      }
    }
  };

  // ---- prologue: xw(0); LIF1(0); publish m1(0); barrier; arrive 1; poll ----
#pragma unroll
  for (int r = 0; r < SPW; ++r) {
    if constexpr (UXW) {
      f32x4 a = __builtin_nontemporal_load(
          (const f32x4*)(XWc + (size_t)(s0 + r) * HD));
      xw[r][0] = a.x; xw[r][1] = a.y; xw[r][2] = a.z; xw[r][3] = a.w;
    } else {
      compute_xw(0, r);
    }
    nib1[r] = lif_update(xw[r], syn1[r], mem1[r], 0u);
    u64 E0 = __ballot(nib1[r] & 1u), E1 = __ballot(nib1[r] & 2u);
    u64 E2 = __ballot(nib1[r] & 4u), E3 = __ballot(nib1[r] & 8u);
    if (lane < 4)
      __hip_atomic_store(&m1W[(size_t)(s0 + r) * NWPS + 4 * x + lane],
                         pack_word(E0, E1, E2, E3, lane), __ATOMIC_RELAXED,
                         __HIP_MEMORY_SCOPE_AGENT);
  }
  __syncthreads();
  if (tid == 0)
    __hip_atomic_store(SLOT(slots, g, x), 1u, __ATOMIC_RELAXED,
                       __HIP_MEMORY_SCOPE_AGENT);
  __syncthreads();
  if (tid == 0) {
    while (true) {
      u32 mn = 0xffffffffu;
#pragma unroll
      for (int x2 = 0; x2 < 8; ++x2) {
        u32 v = __hip_atomic_load(SLOT(slots, g, x2), __ATOMIC_RELAXED,
                                  __HIP_MEMORY_SCOPE_AGENT);
        mn = v < mn ? v : mn;
      }
      if (mn >= 1u) break;
      __builtin_amdgcn_s_sleep(1);
    }
  }
  __syncthreads();

  // ---- main loop: step s gathers with m1(s); xw holds t((s+1)) ----
  for (int s = 0; s < NSTEPS; ++s) {
    const bool last = (s == NSTEPS - 1);
    if (s & 1) {
#pragma unroll
      for (int r = 0; r < SPW; ++r) {
        if constexpr (UXW) {
          xw[r][0] = xwN[r].x; xw[r][1] = xwN[r].y;
          xw[r][2] = xwN[r].z; xw[r][3] = xwN[r].w;
        } else {
          if (s + 1 < NSTEPS) compute_xw((s + 1) >> 1, r);
        }
      }
    }

    const u64* m1cur = m1W + (size_t)(s & 1) * NB * NWPS;
    u64* m1n = m1W + (size_t)((s + 1) & 1) * NB * NWPS;

    __builtin_amdgcn_s_setprio(1);
#pragma unroll
    for (int r = 0; r < SPW; ++r) {
      const int smp = s0 + r;
      int r8 = build_one(m1cur + (size_t)smp * NWPS, lst, lane);
      float aV[4] = {xw[r][0], xw[r][1], xw[r][2], xw[r][3]};
      float aW[4] = {bfr[0], bfr[1], bfr[2], bfr[3]};
      gather_one(PKb, lst, r8, aV, aW);

      nib2[r] = lif_update(aW, syn2[r], mem2[r], nib2[r]);
      if (!last) nib1[r] = lif_update(aV, syn1[r], mem1[r], nib1[r]);

      u64 D0 = __ballot(nib2[r] & 1u), D1 = __ballot(nib2[r] & 2u);
      u64 D2 = __ballot(nib2[r] & 4u), D3 = __ballot(nib2[r] & 8u);
      u64 E0 = __ballot(nib1[r] & 1u), E1 = __ballot(nib1[r] & 2u);
      u64 E2 = __ballot(nib1[r] & 4u), E3 = __ballot(nib1[r] & 8u);
      if (lane < 4) {
        __hip_atomic_store(&m2H[((size_t)s * NB + smp) * NWPS + 4 * x + lane],
                           pack_word(D0, D1, D2, D3, lane), __ATOMIC_RELAXED,
                           __HIP_MEMORY_SCOPE_AGENT);
        if (!last)
          __hip_atomic_store(&m1n[(size_t)smp * NWPS + 4 * x + lane],
                             pack_word(E0, E1, E2, E3, lane), __ATOMIC_RELAXED,
                             __HIP_MEMORY_SCOPE_AGENT);
      }
    }
    __builtin_amdgcn_s_setprio(0);

    if (!last) {
      __syncthreads();   // single merged drain (m2H + m1n)
      if (tid == 0)
        __hip_atomic_store(SLOT(slots, g, x), (u32)(s + 2), __ATOMIC_RELAXED,
                           __HIP_MEMORY_SCOPE_AGENT);
      // shadow: xw prefetch under the poll window
      if ((s & 1) == 0) {
        if constexpr (UXW) {
          int t2 = (s >> 1) + 1;
          if (t2 < 64) {
#pragma unroll
            for (int r = 0; r < SPW; ++r)
              xwN[r] = __builtin_nontemporal_load(
                  (const f32x4*)(XWc + ((size_t)t2 * NB + s0 + r) * HD));
          }
        }
      }
      if (tid == 0) {
        while (true) {
          u32 mn = 0xffffffffu;
#pragma unroll
          for (int x2 = 0; x2 < 8; ++x2) {
            u32 v = __hip_atomic_load(SLOT(slots, g, x2), __ATOMIC_RELAXED,
                                      __HIP_MEMORY_SCOPE_AGENT);
            mn = v < mn ? v : mn;
          }
          if (mn >= (u32)(s + 2)) break;
          __builtin_amdgcn_s_sleep(1);
        }
      }
      __syncthreads();
    }
  }

  // ---- final rendezvous (full fence once) ----
  __syncthreads();
  if (tid == 0) {
    __threadfence();
    __hip_atomic_fetch_add(done, 1u, __ATOMIC_RELEASE, __HIP_MEMORY_SCOPE_AGENT);
    while (__hip_atomic_load(done, __ATOMIC_RELAXED,
                             __HIP_MEMORY_SCOPE_AGENT) < (u32)gridDim.x)
      __builtin_amdgcn_s_sleep(8);
    __threadfence();
  }
  __syncthreads();

  // ---- deferred readout: SPW waves/block, wave = one sample ----
  if (wv < SPW) {
    const int rsmp = blockIdx.x * SPW + wv;
    const float bor = bo[lane];
    float synr = 0.f, memr = 0.f, roprev = 0.f;
    for (int s = 0; s < NSTEPS; ++s) {
      int total = build_list_ro(m2H + ((size_t)s * NB + rsmp) * NWPS, lst, lane);
      float a = bor;
      for (int j0 = 0; j0 < total; j0 += 8) {
        float vv[8];
#pragma unroll
        for (int u = 0; u < 8; ++u) {
          int idx = j0 + u;
          if (idx >= total) idx = j0;
          vv[u] = Wo[(((size_t)lst[idx]) << 6) + lane];
        }
#pragma unroll
        for (int u = 0; u < 8; ++u)
          if (j0 + u < total) a += vv[u];
      }
      float nmemr = DMc * memr + SMc * synr;  // R1 shape
      float nsynr = DSc * synr + a;           // R1 shape
      memr = nmemr;
      synr = nsynr;
      if (s & 1) {
        float v = 0.5f * (roprev + nmemr);
        size_t base = ((size_t)(s >> 1) * NB + rsmp) * 32;
        if (lane < 32) out[base + lane] = v;
        else out[(size_t)64 * NB * 32 + base + (lane - 32)] = v;
      } else {
        roprev = nmemr;
      }
    }
  }
}

extern "C" void kernel_launch(void* const* d_in, const int* in_sizes, int n_in,
                              void* d_out, int out_size, void* d_ws, size_t ws_size,
                              hipStream_t stream) {
  const float* state  = (const float*)d_in[0];
  const float* target = (const float*)d_in[1];
  const float* Wi     = (const float*)d_in[2];
  const float* bi     = (const float*)d_in[3];
  const float* Vr     = (const float*)d_in[4];
  const float* Wf     = (const float*)d_in[5];
  const float* bf     = (const float*)d_in[6];
  const float* Wo     = (const float*)d_in[7];
  const float* bo     = (const float*)d_in[8];
  float* out = (float*)d_out;
  char* wsb = (char*)d_ws;

  const int use_xw = (ws_size >= OFF_XW + SZ_XW) ? 1 : 0;

  // can we co-schedule 2 blocks/CU? (deterministic host-side query)
  int nb = 0;
  (void)hipOccupancyMaxActiveBlocksPerMultiprocessor(&nb, rsnn_coop<1, 1>,
                                                     THREADS, 0);
  const int spw1 = (nb >= 2) ? 1 : 0;

  init_ws<<<128, 256, 0, stream>>>((u64*)(wsb + OFF_M1W), (u32*)(wsb + OFF_SLOT),
                                   (u32*)(wsb + OFF_DONE));
  pack_kernel<<<ROWS, 256, 0, stream>>>(Vr, Wf, (float*)(wsb + OFF_PK));
  if (use_xw)
    xw_kernel<<<dim3(8, 2048), 256, 0, stream>>>(state, target, Wi, bi,
                                                 (float*)(wsb + OFF_XW));

  void* args[] = {(void*)&state, (void*)&target, (void*)&Wi, (void*)&bi,
                  (void*)&Vr, (void*)&Wf, (void*)&bf, (void*)&Wo, (void*)&bo,
                  (void*)&out, (void*)&wsb};
  if (spw1) {
    if (use_xw)
      (void)hipLaunchCooperativeKernel(rsnn_coop<1, 1>, dim3(512), dim3(THREADS),
                                       args, 0, stream);
    else
      (void)hipLaunchCooperativeKernel(rsnn_coop<1, 0>, dim3(512), dim3(THREADS),
                                       args, 0, stream);
  } else {
    if (use_xw)
      (void)hipLaunchCooperativeKernel(rsnn_coop<2, 1>, dim3(256), dim3(THREADS),
                                       args, 0, stream);
    else
      (void)hipLaunchCooperativeKernel(rsnn_coop<2, 0>, dim3(256), dim3(THREADS),
                                       args, 0, stream);
  }
}

// Round 15
// 9701.258 us; speedup vs baseline: 1.3594x; 1.3594x over previous
//
#include <hip/hip_runtime.h>
#include <stdint.h>

// PolicyNetRSNNPB R15 = R14 with __launch_bounds__(512,2).
// The round-by-round ledger shows VGPR is the hidden variable:
//   64-VGPR builds (R6,R8,R13,R14): serialized gather, FETCH 14-20GB, 8-10ms
//  128-VGPR builds (R5,R9,R11,R12): pipelined gather, FETCH <3GB, 3.6-5.6ms
// R14's launch_bounds(512,4) forced 64 VGPR and poisoned the 2-blocks/CU
// experiment. R15 reruns it at (512,2) (empirically -> 128 VGPR): 2 blocks/CU
// x 8 waves = 16 waves/CU of independent group-chains, full 16-deep gather
// pipeline. Occupancy query falls back to grid-256/SPW=2 (R11 geometry) if
// 2 blocks/CU doesn't hold. Bit-exact order preserved (absmax 0.0 so far).

typedef unsigned long long u64;
typedef unsigned int u32;
typedef float f32x4 __attribute__((ext_vector_type(4)));

#define NB 512
#define HD 2048
#define ROWS 2049          // 2048 + zero row
#define NSTEPS 128
#define THREADS 512
#define COLS 256
#define NWPS 32
#define LSTN 2080          // 8*2080*2B = 33,280B LDS -> 2 blocks/CU possible
#define ZROW 2048

#define DMc 0.8187307530779818f
#define DSc 0.6065306597126334f
#define SMc 0.18126924692201818f

// ---- ws layout ----
#define OFF_M1W 0
#define SZ_M1W ((size_t)2 * NB * NWPS * 8)       // 256 KB
#define OFF_M2H (OFF_M1W + SZ_M1W)
#define SZ_M2H ((size_t)NSTEPS * NB * NWPS * 8)  // 16 MB
#define OFF_SLOT (OFF_M2H + SZ_M2H)              // u32 per (g,x), 128B stride
#define SZ_SLOT (64 * 8 * 128)
#define OFF_DONE (OFF_SLOT + SZ_SLOT)
#define OFF_PK (((size_t)(OFF_DONE + 64) + 4194303) & ~(size_t)4194303)
#define SZ_PK ((size_t)8 * ROWS * 512 * 4)       // ~33.6 MB
#define OFF_XW (((OFF_PK + SZ_PK) + 255) & ~(size_t)255)
#define SZ_XW ((size_t)64 * NB * HD * 4)         // 256 MB

#define SLOT(base, g, x) ((base) + ((size_t)((g)*8 + (x)) * 32))

__global__ void init_ws(u64* __restrict__ m1W, u32* __restrict__ slots,
                        u32* __restrict__ done) {
  int i = blockIdx.x * 256 + threadIdx.x;
  if (i < 2 * NB * NWPS) m1W[i] = 0ULL;
  if (i < 64 * 8 * 32) slots[i] = 0u;
  if (i == 0) *done = 0u;
}

// PK[x][k][0..255]=Vr[k][x*256+..], [256..511]=Wf[k][..]; row 2048 = zeros
__global__ __launch_bounds__(256) void pack_kernel(
    const float* __restrict__ Vr, const float* __restrict__ Wf,
    float* __restrict__ PK) {
  const int k = blockIdx.x;
  const int tid = threadIdx.x;
  for (int c = tid; c < HD; c += 256) {
    int x = c >> 8, cc = c & 255;
    size_t base = ((size_t)x * ROWS + k) * 512;
    float v = (k < HD) ? Vr[(size_t)k * HD + c] : 0.0f;
    float w = (k < HD) ? Wf[(size_t)k * HD + c] : 0.0f;
    __builtin_nontemporal_store(v, &PK[base + cc]);
    __builtin_nontemporal_store(w, &PK[base + 256 + cc]);
  }
}

// XW[t*NB+n][h] = bi[h] + x(t,n,:) @ Wi
__global__ __launch_bounds__(256) void xw_kernel(
    const float* __restrict__ state, const float* __restrict__ target,
    const float* __restrict__ Wi, const float* __restrict__ bi,
    float* __restrict__ XW) {
  __shared__ float xl[16][128];
  const int tid = threadIdx.x;
  const int col = blockIdx.x * 256 + tid;
  const int r0 = blockIdx.y * 16;

  for (int idx = tid; idx < 16 * 128; idx += 256) {
    int r = idx >> 7, k = idx & 127;
    int gg = r0 + r;
    int t = gg >> 9, n = gg & 511;
    float v = (k < 64) ? state[((size_t)(t * NB + n)) * 64 + k]
                       : target[((size_t)(t * NB + n)) * 64 + (k - 64)];
    xl[r][k] = v;
  }
  __syncthreads();

  float acc[16];
  float b = bi[col];
#pragma unroll
  for (int r = 0; r < 16; ++r) acc[r] = b;
  for (int k = 0; k < 128; ++k) {
    float w = Wi[(size_t)k * HD + col];
#pragma unroll
    for (int r = 0; r < 16; ++r) acc[r] = fmaf(xl[r][k], w, acc[r]);
  }
#pragma unroll
  for (int r = 0; r < 16; ++r)
    __builtin_nontemporal_store(acc[r], &XW[(size_t)(r0 + r) * HD + col]);
}

__device__ __forceinline__ u64 spread4(u64 x) {
  x &= 0xffffULL;
  x = (x | (x << 24)) & 0x000000FF000000FFULL;
  x = (x | (x << 12)) & 0x000F000F000F000FULL;
  x = (x | (x << 6))  & 0x0303030303030303ULL;
  x = (x | (x << 3))  & 0x1111111111111111ULL;
  return x;
}

__device__ __forceinline__ u64 pack_word(u64 B0, u64 B1, u64 B2, u64 B3, int q) {
  int sh = q * 16;
  return spread4(B0 >> sh) | (spread4(B1 >> sh) << 1) |
         (spread4(B2 >> sh) << 2) | (spread4(B3 >> sh) << 3);
}

// one-sample list build from MALL masks; ascending; pad to x8 with ZROW.
__device__ __forceinline__ int build_one(const u64* __restrict__ mw,
                                         uint16_t* __restrict__ lst, int lane) {
  u64 w = 0ULL;
  if (lane < NWPS)
    w = __hip_atomic_load((u64*)&mw[lane], __ATOMIC_RELAXED,
                          __HIP_MEMORY_SCOPE_AGENT);
  int pc = __popcll(w);
  int pre = pc;
#pragma unroll
  for (int off = 1; off < 64; off <<= 1) {
    int v = __shfl_up(pre, off);
    if (lane >= off) pre += v;
  }
  int excl = pre - pc;
  int total = __shfl(pre, 63);
  int kb = lane << 6;
  while (w) {
    int b = __builtin_ctzll(w);
    w &= w - 1;
    lst[excl++] = (uint16_t)(kb + b);
  }
  int r8 = (total + 7) & ~7;
  if (lane < 8 && total + lane < r8) lst[total + lane] = (uint16_t)ZROW;
  asm volatile("s_waitcnt lgkmcnt(0)" ::: "memory");
  return r8;
}

// readout-tail list build (plain loads)
__device__ __forceinline__ int build_list_ro(const u64* __restrict__ mwords,
                                             uint16_t* __restrict__ lstw,
                                             int lane) {
  u64 w = (lane < NWPS) ? mwords[lane] : 0ULL;
  int pc = __popcll(w);
  int pre = pc;
#pragma unroll
  for (int off = 1; off < 64; off <<= 1) {
    int v = __shfl_up(pre, off);
    if (lane >= off) pre += v;
  }
  int excl = pre - pc;
  int total = __shfl(pre, 63);
  int kb = lane << 6;
  while (w) {
    int b = __builtin_ctzll(w);
    w &= w - 1;
    lstw[excl++] = (uint16_t)(kb + b);
  }
  asm volatile("s_waitcnt lgkmcnt(0)" ::: "memory");
  return total;
}

__device__ __forceinline__ u32 lif_update(const float acc[4], float syn[4],
                                          float mem[4], u32 snib) {
  u32 nib = 0;
#pragma unroll
  for (int j = 0; j < 4; ++j) {
    float so = (float)((snib >> j) & 1u);
    float nmem = (DMc * mem[j] + SMc * syn[j]) * (1.0f - so);  // R1 shape
    float nsyn = DSc * syn[j] + acc[j];                         // R1 shape
    mem[j] = nmem;
    syn[j] = nsyn;
    if ((nmem - 1.0f) > 0.0f) nib |= (1u << j);
  }
  return nib;
}

// unguarded dual gather (zero-row padded list): addr + 2 loads + 8 adds per
// element, 16 loads in flight, ascending k; trailing +0.0 adds exact.
__device__ __forceinline__ void gather_one(const float* __restrict__ PKb,
                                           const uint16_t* __restrict__ lst,
                                           int r8, float aV[4], float aW[4]) {
  for (int j0 = 0; j0 < r8; j0 += 8) {
    f32x4 v[8], w8[8];
#pragma unroll
    for (int u = 0; u < 8; ++u) {
      size_t off = ((size_t)lst[j0 + u]) << 9;
      v[u] = *(const f32x4*)(PKb + off);
      w8[u] = *(const f32x4*)(PKb + off + 256);
    }
#pragma unroll
    for (int u = 0; u < 8; ++u) {
      aV[0] += v[u].x; aV[1] += v[u].y; aV[2] += v[u].z; aV[3] += v[u].w;
      aW[0] += w8[u].x; aW[1] += w8[u].y; aW[2] += w8[u].z; aW[3] += w8[u].w;
    }
  }
}

// SPW = samples per wave (1: grid 512, 2 blocks/CU; 2: grid 256 fallback)
template <int SPW, int UXW>
__global__ __launch_bounds__(THREADS, 2) void rsnn_coop(
    const float* __restrict__ state, const float* __restrict__ target,
    const float* __restrict__ Wi, const float* __restrict__ bi,
    const float* __restrict__ Vr, const float* __restrict__ Wf,
    const float* __restrict__ bf, const float* __restrict__ Wo,
    const float* __restrict__ bo, float* __restrict__ out,
    char* __restrict__ wsb) {
  __shared__ uint16_t lst_s[8][LSTN];   // 33,280 B

  u64* m1W = (u64*)(wsb + OFF_M1W);
  u64* m2H = (u64*)(wsb + OFF_M2H);
  u32* slots = (u32*)(wsb + OFF_SLOT);
  u32* done = (u32*)(wsb + OFF_DONE);
  const float* PK = (const float*)(wsb + OFF_PK);
  const float* XW = (const float*)(wsb + OFF_XW);

  const int tid = threadIdx.x;
  const int wv = tid >> 6;      // 0..7
  const int lane = tid & 63;    // lane = 4 columns

  const int x = blockIdx.x & 7;          // column-slice owner (~physical XCD)
  const int g = blockIdx.x >> 3;         // group id
  const int c0 = x * COLS;
  const int s0 = (g * 8 + wv) * SPW;     // first sample of this wave

  uint16_t* lst = &lst_s[wv][0];

  float bir[4], bfr[4];
#pragma unroll
  for (int j = 0; j < 4; ++j) {
    bir[j] = bi[c0 + lane * 4 + j];
    bfr[j] = bf[c0 + lane * 4 + j];
  }

  float syn1[SPW][4], mem1[SPW][4], syn2[SPW][4], mem2[SPW][4];
#pragma unroll
  for (int r = 0; r < SPW; ++r)
#pragma unroll
    for (int j = 0; j < 4; ++j) {
      syn1[r][j] = 0.f; mem1[r][j] = 0.f; syn2[r][j] = 0.f; mem2[r][j] = 0.f;
    }
  u32 nib1[SPW], nib2[SPW];
#pragma unroll
  for (int r = 0; r < SPW; ++r) { nib1[r] = 0u; nib2[r] = 0u; }
  float xw[SPW][4];
  f32x4 xwN[SPW];

  const float* PKb = PK + (size_t)x * ROWS * 512 + lane * 4;
  const float* XWc = XW + c0 + lane * 4;

  // fallback xw (k-ascending fmaf from global Wi)
  auto compute_xw = [&](int t2, int r) {
#pragma unroll
    for (int j = 0; j < 4; ++j) xw[r][j] = bir[j];
#pragma unroll
    for (int half = 0; half < 2; ++half) {
      const float* p =
          (half ? target : state) + ((size_t)t2 * NB + s0 + r) * 64;
      for (int q = 0; q < 16; ++q) {
        f32x4 xq = *(const f32x4*)(p + 4 * q);
        float xv[4] = {xq.x, xq.y, xq.z, xq.w};
#pragma unroll
        for (int kj = 0; kj < 4; ++kj) {
          const f32x4 w4 = *(const f32x4*)&Wi[(size_t)(half * 64 + 4 * q + kj) *
                                                  HD + c0 + lane * 4];
          xw[r][0] = fmaf(xv[kj], w4.x, xw[r][0]);
          xw[r][1] = fmaf(xv[kj], w4.y, xw[r][1]);
          xw[r][2] = fmaf(xv[kj], w4.z, xw[r][2]);
          xw[r][3] = fmaf(xv[kj], w4.w, xw[r][3]);
        }
      }
    }
  };

  // ---- prologue: xw(0); LIF1(0); publish m1(0); barrier; arrive 1; poll ----
#pragma unroll
  for (int r = 0; r < SPW; ++r) {
    if constexpr (UXW) {
      f32x4 a = __builtin_nontemporal_load(
          (const f32x4*)(XWc + (size_t)(s0 + r) * HD));
      xw[r][0] = a.x; xw[r][1] = a.y; xw[r][2] = a.z; xw[r][3] = a.w;
    } else {
      compute_xw(0, r);
    }
    nib1[r] = lif_update(xw[r], syn1[r], mem1[r], 0u);
    u64 E0 = __ballot(nib1[r] & 1u), E1 = __ballot(nib1[r] & 2u);
    u64 E2 = __ballot(nib1[r] & 4u), E3 = __ballot(nib1[r] & 8u);
    if (lane < 4)
      __hip_atomic_store(&m1W[(size_t)(s0 + r) * NWPS + 4 * x + lane],
                         pack_word(E0, E1, E2, E3, lane), __ATOMIC_RELAXED,
                         __HIP_MEMORY_SCOPE_AGENT);
  }
  __syncthreads();
  if (tid == 0)
    __hip_atomic_store(SLOT(slots, g, x), 1u, __ATOMIC_RELAXED,
                       __HIP_MEMORY_SCOPE_AGENT);
  __syncthreads();
  if (tid == 0) {
    while (true) {
      u32 mn = 0xffffffffu;
#pragma unroll
      for (int x2 = 0; x2 < 8; ++x2) {
        u32 v = __hip_atomic_load(SLOT(slots, g, x2), __ATOMIC_RELAXED,
                                  __HIP_MEMORY_SCOPE_AGENT);
        mn = v < mn ? v : mn;
      }
      if (mn >= 1u) break;
      __builtin_amdgcn_s_sleep(1);
    }
  }
  __syncthreads();

  // ---- main loop: step s gathers with m1(s); xw holds t=(s+1)>>1 ----
  for (int s = 0; s < NSTEPS; ++s) {
    const bool last = (s == NSTEPS - 1);
    if (s & 1) {
#pragma unroll
      for (int r = 0; r < SPW; ++r) {
        if constexpr (UXW) {
          xw[r][0] = xwN[r].x; xw[r][1] = xwN[r].y;
          xw[r][2] = xwN[r].z; xw[r][3] = xwN[r].w;
        } else {
          if (s + 1 < NSTEPS) compute_xw((s + 1) >> 1, r);
        }
      }
    }

    const u64* m1cur = m1W + (size_t)(s & 1) * NB * NWPS;
    u64* m1n = m1W + (size_t)((s + 1) & 1) * NB * NWPS;

    __builtin_amdgcn_s_setprio(1);
#pragma unroll
    for (int r = 0; r < SPW; ++r) {
      const int smp = s0 + r;
      int r8 = build_one(m1cur + (size_t)smp * NWPS, lst, lane);
      float aV[4] = {xw[r][0], xw[r][1], xw[r][2], xw[r][3]};
      float aW[4] = {bfr[0], bfr[1], bfr[2], bfr[3]};
      gather_one(PKb, lst, r8, aV, aW);

      nib2[r] = lif_update(aW, syn2[r], mem2[r], nib2[r]);
      if (!last) nib1[r] = lif_update(aV, syn1[r], mem1[r], nib1[r]);

      u64 D0 = __ballot(nib2[r] & 1u), D1 = __ballot(nib2[r] & 2u);
      u64 D2 = __ballot(nib2[r] & 4u), D3 = __ballot(nib2[r] & 8u);
      u64 E0 = __ballot(nib1[r] & 1u), E1 = __ballot(nib1[r] & 2u);
      u64 E2 = __ballot(nib1[r] & 4u), E3 = __ballot(nib1[r] & 8u);
      if (lane < 4) {
        __hip_atomic_store(&m2H[((size_t)s * NB + smp) * NWPS + 4 * x + lane],
                           pack_word(D0, D1, D2, D3, lane), __ATOMIC_RELAXED,
                           __HIP_MEMORY_SCOPE_AGENT);
        if (!last)
          __hip_atomic_store(&m1n[(size_t)smp * NWPS + 4 * x + lane],
                             pack_word(E0, E1, E2, E3, lane), __ATOMIC_RELAXED,
                             __HIP_MEMORY_SCOPE_AGENT);
      }
    }
    __builtin_amdgcn_s_setprio(0);

    if (!last) {
      __syncthreads();   // single merged drain (m2H + m1n)
      if (tid == 0)
        __hip_atomic_store(SLOT(slots, g, x), (u32)(s + 2), __ATOMIC_RELAXED,
                           __HIP_MEMORY_SCOPE_AGENT);
      // shadow: xw prefetch under the poll window
      if ((s & 1) == 0) {
        if constexpr (UXW) {
          int t2 = (s >> 1) + 1;
          if (t2 < 64) {
#pragma unroll
            for (int r = 0; r < SPW; ++r)
              xwN[r] = __builtin_nontemporal_load(
                  (const f32x4*)(XWc + ((size_t)t2 * NB + s0 + r) * HD));
          }
        }
      }
      if (tid == 0) {
        while (true) {
          u32 mn = 0xffffffffu;
#pragma unroll
          for (int x2 = 0; x2 < 8; ++x2) {
            u32 v = __hip_atomic_load(SLOT(slots, g, x2), __ATOMIC_RELAXED,
                                      __HIP_MEMORY_SCOPE_AGENT);
            mn = v < mn ? v : mn;
          }
          if (mn >= (u32)(s + 2)) break;
          __builtin_amdgcn_s_sleep(1);
        }
      }
      __syncthreads();
    }
  }

  // ---- final rendezvous (full fence once) ----
  __syncthreads();
  if (tid == 0) {
    __threadfence();
    __hip_atomic_fetch_add(done, 1u, __ATOMIC_RELEASE, __HIP_MEMORY_SCOPE_AGENT);
    while (__hip_atomic_load(done, __ATOMIC_RELAXED,
                             __HIP_MEMORY_SCOPE_AGENT) < (u32)gridDim.x)
      __builtin_amdgcn_s_sleep(8);
    __threadfence();
  }
  __syncthreads();

  // ---- deferred readout: SPW waves/block, wave = one sample ----
  if (wv < SPW) {
    const int rsmp = blockIdx.x * SPW + wv;
    const float bor = bo[lane];
    float synr = 0.f, memr = 0.f, roprev = 0.f;
    for (int s = 0; s < NSTEPS; ++s) {
      int total = build_list_ro(m2H + ((size_t)s * NB + rsmp) * NWPS, lst, lane);
      float a = bor;
      for (int j0 = 0; j0 < total; j0 += 8) {
        float vv[8];
#pragma unroll
        for (int u = 0; u < 8; ++u) {
          int idx = j0 + u;
          if (idx >= total) idx = j0;
          vv[u] = Wo[(((size_t)lst[idx]) << 6) + lane];
        }
#pragma unroll
        for (int u = 0; u < 8; ++u)
          if (j0 + u < total) a += vv[u];
      }
      float nmemr = DMc * memr + SMc * synr;  // R1 shape
      float nsynr = DSc * synr + a;           // R1 shape
      memr = nmemr;
      synr = nsynr;
      if (s & 1) {
        float v = 0.5f * (roprev + nmemr);
        size_t base = ((size_t)(s >> 1) * NB + rsmp) * 32;
        if (lane < 32) out[base + lane] = v;
        else out[(size_t)64 * NB * 32 + base + (lane - 32)] = v;
      } else {
        roprev = nmemr;
      }
    }
  }
}

extern "C" void kernel_launch(void* const* d_in, const int* in_sizes, int n_in,
                              void* d_out, int out_size, void* d_ws, size_t ws_size,
                              hipStream_t stream) {
  const float* state  = (const float*)d_in[0];
  const float* target = (const float*)d_in[1];
  const float* Wi     = (const float*)d_in[2];
  const float* bi     = (const float*)d_in[3];
  const float* Vr     = (const float*)d_in[4];
  const float* Wf     = (const float*)d_in[5];
  const float* bf     = (const float*)d_in[6];
  const float* Wo     = (const float*)d_in[7];
  const float* bo     = (const float*)d_in[8];
  float* out = (float*)d_out;
  char* wsb = (char*)d_ws;

  const int use_xw = (ws_size >= OFF_XW + SZ_XW) ? 1 : 0;

  // can we co-schedule 2 blocks/CU? (deterministic host-side query)
  int nb = 0;
  if (use_xw)
    (void)hipOccupancyMaxActiveBlocksPerMultiprocessor(&nb, rsnn_coop<1, 1>,
                                                       THREADS, 0);
  else
    (void)hipOccupancyMaxActiveBlocksPerMultiprocessor(&nb, rsnn_coop<1, 0>,
                                                       THREADS, 0);
  const int spw1 = (nb >= 2) ? 1 : 0;

  init_ws<<<128, 256, 0, stream>>>((u64*)(wsb + OFF_M1W), (u32*)(wsb + OFF_SLOT),
                                   (u32*)(wsb + OFF_DONE));
  pack_kernel<<<ROWS, 256, 0, stream>>>(Vr, Wf, (float*)(wsb + OFF_PK));
  if (use_xw)
    xw_kernel<<<dim3(8, 2048), 256, 0, stream>>>(state, target, Wi, bi,
                                                 (float*)(wsb + OFF_XW));

  void* args[] = {(void*)&state, (void*)&target, (void*)&Wi, (void*)&bi,
                  (void*)&Vr, (void*)&Wf, (void*)&bf, (void*)&Wo, (void*)&bo,
                  (void*)&out, (void*)&wsb};
  if (spw1) {
    if (use_xw)
      (void)hipLaunchCooperativeKernel(rsnn_coop<1, 1>, dim3(512), dim3(THREADS),
                                       args, 0, stream);
    else
      (void)hipLaunchCooperativeKernel(rsnn_coop<1, 0>, dim3(512), dim3(THREADS),
                                       args, 0, stream);
  } else {
    if (use_xw)
      (void)hipLaunchCooperativeKernel(rsnn_coop<2, 1>, dim3(256), dim3(THREADS),
                                       args, 0, stream);
    else
      (void)hipLaunchCooperativeKernel(rsnn_coop<2, 0>, dim3(256), dim3(THREADS),
                                       args, 0, stream);
  }
}